// Round 1
// baseline (661.552 us; speedup 1.0000x reference)
//
#include <hip/hip_runtime.h>
#include <hip/hip_bf16.h>

// ---------- types ----------
typedef __bf16 bf16x8 __attribute__((ext_vector_type(8)));
typedef float  f32x4  __attribute__((ext_vector_type(4)));
typedef unsigned short u16;

__device__ __forceinline__ u16 f2bf(float f) {
    __hip_bfloat16 h = __float2bfloat16(f);   // RNE
    return __builtin_bit_cast(unsigned short, h);
}

// mode: 0=sum, 1=max, 2=min   (256-thread blocks = 4 waves)
template <int MODE>
__device__ __forceinline__ float blockReduce(float v, float* sbuf) {
    #pragma unroll
    for (int off = 32; off > 0; off >>= 1) {
        float o = __shfl_down(v, off, 64);
        v = (MODE == 0) ? v + o : (MODE == 1) ? fmaxf(v, o) : fminf(v, o);
    }
    int lane = threadIdx.x & 63, w = threadIdx.x >> 6;
    __syncthreads();                 // protect sbuf from previous use
    if (lane == 0) sbuf[w] = v;
    __syncthreads();
    float r = sbuf[0];
    #pragma unroll
    for (int i = 1; i < 4; ++i) {
        float o = sbuf[i];
        r = (MODE == 0) ? r + o : (MODE == 1) ? fmaxf(r, o) : fminf(r, o);
    }
    return r;
}

// ---------- prep: fp32 row -> bf16 row (+ optional row sum-of-squares), zero-pad rows ----------
// cols fixed = 2048, 256 threads, 8 elems/thread
__global__ void convert_rowsq(const float* __restrict__ src, u16* __restrict__ dst,
                              float* __restrict__ rowsq, int validRows) {
    __shared__ float sbuf[4];
    int r = blockIdx.x, t = threadIdx.x;
    size_t base = (size_t)r * 2048 + t * 8;
    float ss = 0.f;
    ushort4 u0 = {0,0,0,0}, u1 = {0,0,0,0};
    if (r < validRows) {
        float4 a0 = *(const float4*)(src + base);
        float4 a1 = *(const float4*)(src + base + 4);
        ss = a0.x*a0.x + a0.y*a0.y + a0.z*a0.z + a0.w*a0.w
           + a1.x*a1.x + a1.y*a1.y + a1.z*a1.z + a1.w*a1.w;
        u0.x = f2bf(a0.x); u0.y = f2bf(a0.y); u0.z = f2bf(a0.z); u0.w = f2bf(a0.w);
        u1.x = f2bf(a1.x); u1.y = f2bf(a1.y); u1.z = f2bf(a1.z); u1.w = f2bf(a1.w);
    }
    *(ushort4*)(dst + base)     = u0;
    *(ushort4*)(dst + base + 4) = u1;
    if (rowsq != nullptr) {
        ss = blockReduce<0>(ss, sbuf);
        if (t == 0) rowsq[r] = ss;
    }
}

// ---------- prep: W_cos row-normalize -> bf16, zero-pad rows ----------
__global__ void norm_rows(const float* __restrict__ src, u16* __restrict__ dst, int validRows) {
    __shared__ float sbuf[4];
    int r = blockIdx.x, t = threadIdx.x;
    size_t base = (size_t)r * 2048 + t * 8;
    ushort4 u0 = {0,0,0,0}, u1 = {0,0,0,0};
    if (r < validRows) {
        float4 a0 = *(const float4*)(src + base);
        float4 a1 = *(const float4*)(src + base + 4);
        float ss = a0.x*a0.x + a0.y*a0.y + a0.z*a0.z + a0.w*a0.w
                 + a1.x*a1.x + a1.y*a1.y + a1.z*a1.z + a1.w*a1.w;
        ss = blockReduce<0>(ss, sbuf);
        float sc = 1.f / sqrtf(ss);
        u0.x = f2bf(a0.x*sc); u0.y = f2bf(a0.y*sc); u0.z = f2bf(a0.z*sc); u0.w = f2bf(a0.w*sc);
        u1.x = f2bf(a1.x*sc); u1.y = f2bf(a1.y*sc); u1.z = f2bf(a1.z*sc); u1.w = f2bf(a1.w*sc);
    }
    *(ushort4*)(dst + base)     = u0;
    *(ushort4*)(dst + base + 4) = u1;
}

// ---------- prep: centroids [1000,2048] fp32 -> centT [2048,1024] bf16 (transposed, K-padded) ----------
__global__ void transpose_to_bf16(const float* __restrict__ src, u16* __restrict__ dst, int validRows) {
    __shared__ u16 tile[32][33];
    int d0 = blockIdx.x * 32;   // feature base (src col)
    int c0 = blockIdx.y * 32;   // class base  (src row)
    int tx = threadIdx.x, ty = threadIdx.y;
    #pragma unroll
    for (int k = 0; k < 4; ++k) {
        int c = c0 + ty + k * 8;
        float v = (c < validRows) ? src[(size_t)c * 2048 + d0 + tx] : 0.f;
        tile[ty + k * 8][tx] = f2bf(v);
    }
    __syncthreads();
    #pragma unroll
    for (int k = 0; k < 4; ++k) {
        int d = d0 + ty + k * 8;
        dst[(size_t)d * 1024 + c0 + tx] = tile[tx][ty + k * 8];
    }
}

// ---------- GEMM: C[M,N] = A[M,K]bf16 @ Bt[N,K]bf16^T, fp32 accum, m97-pattern ----------
// 128x128 tile, BK=64, 256 threads (4 waves, 2x2), each wave 64x64 via 4x4 of 16x16x32 MFMA.
// EPI: 0 = plain store; 2 = tanh(acc+bias[col]) * aux[row,col] (infused); 3 = 16*acc, store col<nValid
template <int EPI>
__global__ __launch_bounds__(256, 2)
void gemm_bt(const u16* __restrict__ A, const u16* __restrict__ Bt, float* __restrict__ C,
             int K, int ldc, int nValid,
             const float* __restrict__ bias, const float* __restrict__ aux) {
    __shared__ u16 As[128 * 64];
    __shared__ u16 Bs[128 * 64];
    const int tid  = threadIdx.x;
    const int lane = tid & 63;
    const int w    = tid >> 6;
    const int wr   = w >> 1, wc = w & 1;
    const int quad = lane >> 4, r16 = lane & 15;
    const int lr   = lane >> 3;          // staging: row within 8-row chunk
    const int lk   = (lane & 7) * 8;     // staging: k element offset (16B)
    const size_t rowBase = (size_t)blockIdx.y * 128;
    const size_t colBase = (size_t)blockIdx.x * 128;

    f32x4 acc[4][4] = {};

    for (int kt = 0; kt < K; kt += 64) {
        #pragma unroll
        for (int i = 0; i < 4; ++i) {
            int ci = w * 4 + i;   // chunk 0..15, 8 rows each
            const u16* ga = A  + (rowBase + ci * 8 + lr) * (size_t)K + kt + lk;
            const u16* gb = Bt + (colBase + ci * 8 + lr) * (size_t)K + kt + lk;
            __builtin_amdgcn_global_load_lds(
                (const __attribute__((address_space(1))) void*)ga,
                (__attribute__((address_space(3))) void*)(As + ci * 512), 16, 0, 0);
            __builtin_amdgcn_global_load_lds(
                (const __attribute__((address_space(1))) void*)gb,
                (__attribute__((address_space(3))) void*)(Bs + ci * 512), 16, 0, 0);
        }
        __syncthreads();
        #pragma unroll
        for (int kk = 0; kk < 64; kk += 32) {
            bf16x8 a[4], b[4];
            #pragma unroll
            for (int i = 0; i < 4; ++i)
                a[i] = *(const bf16x8*)(As + (wr * 64 + i * 16 + r16) * 64 + kk + quad * 8);
            #pragma unroll
            for (int j = 0; j < 4; ++j)
                b[j] = *(const bf16x8*)(Bs + (wc * 64 + j * 16 + r16) * 64 + kk + quad * 8);
            #pragma unroll
            for (int i = 0; i < 4; ++i)
                #pragma unroll
                for (int j = 0; j < 4; ++j)
                    acc[i][j] = __builtin_amdgcn_mfma_f32_16x16x32_bf16(a[i], b[j], acc[i][j], 0, 0, 0);
        }
        __syncthreads();
    }

    // epilogue: C/D layout col=lane&15, row=quad*4+reg (verified m89/m91)
    #pragma unroll
    for (int i = 0; i < 4; ++i) {
        #pragma unroll
        for (int j = 0; j < 4; ++j) {
            #pragma unroll
            for (int v = 0; v < 4; ++v) {
                size_t grow = rowBase + wr * 64 + i * 16 + quad * 4 + v;
                size_t gcol = colBase + wc * 64 + j * 16 + r16;
                float val = acc[i][j][v];
                if (EPI == 0) {
                    C[grow * (size_t)ldc + gcol] = val;
                } else if (EPI == 2) {
                    float t = tanhf(val + bias[gcol]);
                    C[grow * (size_t)ldc + gcol] = t * aux[grow * (size_t)ldc + gcol];
                } else if (EPI == 3) {
                    if ((int)gcol < nValid) C[grow * (size_t)ldc + gcol] = 16.0f * val;
                }
            }
        }
    }
}

// ---------- min distance -> reachability ----------
__global__ void min_reach(const float* __restrict__ S, const float* __restrict__ xsq,
                          const float* __restrict__ csq, float* __restrict__ reach) {
    __shared__ float sbuf[4];
    int r = blockIdx.x, t = threadIdx.x;
    float m = 1e30f;
    for (int c = t; c < 1000; c += 256)
        m = fminf(m, csq[c] - 2.f * S[(size_t)r * 1024 + c]);
    m = blockReduce<2>(m, sbuf);
    if (t == 0) {
        float d2 = xsq[r] + m;
        reach[r] = 10.f / sqrtf(fmaxf(d2, 0.f));
    }
}

// ---------- softmax over 1000 classes -> bf16 Vm [B,1024] (pad cols = 0) ----------
__global__ void softmax_vm(const float* __restrict__ H, const float* __restrict__ bh,
                           u16* __restrict__ Vm) {
    __shared__ float sbuf[4];
    int r = blockIdx.x, t = threadIdx.x;
    float l[4];
    float m = -1e30f;
    #pragma unroll
    for (int i = 0; i < 4; ++i) {
        int c = t + i * 256;
        l[i] = (c < 1000) ? (H[(size_t)r * 1024 + c] + bh[c]) : -1e30f;
        m = fmaxf(m, l[i]);
    }
    m = blockReduce<1>(m, sbuf);
    float s = 0.f;
    #pragma unroll
    for (int i = 0; i < 4; ++i) {
        int c = t + i * 256;
        l[i] = (c < 1000) ? expf(l[i] - m) : 0.f;
        s += l[i];
    }
    s = blockReduce<0>(s, sbuf);
    float inv = 1.f / s;
    #pragma unroll
    for (int i = 0; i < 4; ++i) {
        int c = t + i * 256;
        Vm[(size_t)r * 1024 + c] = f2bf(l[i] * inv);
    }
}

// ---------- fused = reach*(x+infused); ex = fused/(1+||fused||) -> bf16 ----------
__global__ void fuse_ex(const float* __restrict__ x, const float* __restrict__ inf,
                        const float* __restrict__ reach, u16* __restrict__ exh) {
    __shared__ float sbuf[4];
    int r = blockIdx.x, t = threadIdx.x;
    size_t base = (size_t)r * 2048 + t * 8;
    float4 a0 = *(const float4*)(x + base),   a1 = *(const float4*)(x + base + 4);
    float4 b0 = *(const float4*)(inf + base), b1 = *(const float4*)(inf + base + 4);
    float rr = reach[r];
    float f[8];
    f[0] = rr * (a0.x + b0.x); f[1] = rr * (a0.y + b0.y);
    f[2] = rr * (a0.z + b0.z); f[3] = rr * (a0.w + b0.w);
    f[4] = rr * (a1.x + b1.x); f[5] = rr * (a1.y + b1.y);
    f[6] = rr * (a1.z + b1.z); f[7] = rr * (a1.w + b1.w);
    float ss = 0.f;
    #pragma unroll
    for (int i = 0; i < 8; ++i) ss += f[i] * f[i];
    ss = blockReduce<0>(ss, sbuf);
    float sc = 1.f / (1.f + sqrtf(ss));
    ushort4 u0, u1;
    u0.x = f2bf(f[0]*sc); u0.y = f2bf(f[1]*sc); u0.z = f2bf(f[2]*sc); u0.w = f2bf(f[3]*sc);
    u1.x = f2bf(f[4]*sc); u1.y = f2bf(f[5]*sc); u1.z = f2bf(f[6]*sc); u1.w = f2bf(f[7]*sc);
    *(ushort4*)(exh + base)     = u0;
    *(ushort4*)(exh + base + 4) = u1;
}

extern "C" void kernel_launch(void* const* d_in, const int* in_sizes, int n_in,
                              void* d_out, int out_size, void* d_ws, size_t ws_size,
                              hipStream_t stream) {
    const float* x      = (const float*)d_in[0];   // [8192,2048]
    const float* cent   = (const float*)d_in[1];   // [1000,2048]
    const float* W_hall = (const float*)d_in[2];   // [1000,2048]
    const float* b_hall = (const float*)d_in[3];   // [1000]
    const float* W_sel  = (const float*)d_in[4];   // [2048,2048]
    const float* b_sel  = (const float*)d_in[5];   // [2048]
    const float* W_cos  = (const float*)d_in[6];   // [1000,2048]

    float* out_logits = (float*)d_out;                          // [8192,1000]
    float* out_x      = out_logits + (size_t)8192 * 1000;       // [8192,2048]
    float* out_inf    = out_x      + (size_t)8192 * 2048;       // [8192,2048]

    char* ws = (char*)d_ws;
    u16*   xh      = (u16*)  (ws);                  // 33554432 B  [8192,2048] bf16
    u16*   cent_bt = (u16*)  (ws + 33554432);       //  4194304 B  [1024,2048]
    u16*   whall   = (u16*)  (ws + 37748736);       //  4194304 B  [1024,2048]
    u16*   wsel    = (u16*)  (ws + 41943040);       //  8388608 B  [2048,2048]
    u16*   ew      = (u16*)  (ws + 50331648);       //  4194304 B  [1024,2048]
    u16*   centT   = (u16*)  (ws + 54525952);       //  4194304 B  [2048,1024]
    float* S       = (float*)(ws + 58720256);       // 33554432 B  [8192,1024] (reused: d2-dot, then H)
    u16*   Vm      = (u16*)  (ws + 92274688);       // 16777216 B  [8192,1024]
    float* memf    = (float*)(ws + 109051904);      // 67108864 B  [8192,2048]
    float* xsq     = (float*)(ws + 176160768);      //    32768 B
    float* csq     = (float*)(ws + 176193536);      //     4096 B
    float* reach   = (float*)(ws + 176197632);      //    32768 B
    u16*   exh     = xh;  // alias: xh is dead after the W_sel GEMM

    (void)in_sizes; (void)n_in; (void)out_size; (void)ws_size;

    // direct_feature = x
    hipMemcpyAsync(out_x, x, (size_t)8192 * 2048 * 4, hipMemcpyDeviceToDevice, stream);

    // prep
    convert_rowsq<<<8192, 256, 0, stream>>>(x, xh, xsq, 8192);
    convert_rowsq<<<1024, 256, 0, stream>>>(cent, cent_bt, csq, 1000);
    convert_rowsq<<<1024, 256, 0, stream>>>(W_hall, whall, nullptr, 1000);
    convert_rowsq<<<2048, 256, 0, stream>>>(W_sel, wsel, nullptr, 2048);
    norm_rows<<<1024, 256, 0, stream>>>(W_cos, ew, 1000);
    transpose_to_bf16<<<dim3(64, 32), dim3(32, 8), 0, stream>>>(cent, centT, 1000);

    // S = x @ cent^T  -> reachability
    gemm_bt<0><<<dim3(8, 64), 256, 0, stream>>>(xh, cent_bt, S, 2048, 1024, 0, nullptr, nullptr);
    min_reach<<<8192, 256, 0, stream>>>(S, xsq, csq, reach);

    // S = x @ W_hall^T -> softmax -> Vm (bf16, K-padded)
    gemm_bt<0><<<dim3(8, 64), 256, 0, stream>>>(xh, whall, S, 2048, 1024, 0, nullptr, nullptr);
    softmax_vm<<<8192, 256, 0, stream>>>(S, b_hall, Vm);

    // memf = Vm @ cent   (Bt = centT [2048,1024])
    gemm_bt<0><<<dim3(16, 64), 256, 0, stream>>>(Vm, centT, memf, 1024, 2048, 0, nullptr, nullptr);

    // infused = tanh(x @ W_sel^T + b_sel) * memf   (written straight to output)
    gemm_bt<2><<<dim3(16, 64), 256, 0, stream>>>(xh, wsel, out_inf, 2048, 2048, 0, b_sel, memf);

    // ex = reach*(x+infused) / (1+norm)  -> bf16
    fuse_ex<<<8192, 256, 0, stream>>>(x, out_inf, reach, exh);

    // logits = 16 * ex @ ew^T  (store only cols < 1000)
    gemm_bt<3><<<dim3(8, 64), 256, 0, stream>>>(exh, ew, out_logits, 2048, 1000, 1000, nullptr, nullptr);
}

// Round 2
// 566.621 us; speedup vs baseline: 1.1675x; 1.1675x over previous
//
#include <hip/hip_runtime.h>
#include <hip/hip_bf16.h>

// ---------- types ----------
typedef __bf16 bf16x8 __attribute__((ext_vector_type(8)));
typedef float  f32x4  __attribute__((ext_vector_type(4)));
typedef unsigned short u16;

__device__ __forceinline__ u16 f2bf(float f) {
    __hip_bfloat16 h = __float2bfloat16(f);   // RNE
    return __builtin_bit_cast(unsigned short, h);
}

// mode: 0=sum, 1=max, 2=min   (256-thread blocks = 4 waves)
template <int MODE>
__device__ __forceinline__ float blockReduce(float v, float* sbuf) {
    #pragma unroll
    for (int off = 32; off > 0; off >>= 1) {
        float o = __shfl_down(v, off, 64);
        v = (MODE == 0) ? v + o : (MODE == 1) ? fmaxf(v, o) : fminf(v, o);
    }
    int lane = threadIdx.x & 63, w = threadIdx.x >> 6;
    __syncthreads();                 // protect sbuf from previous use
    if (lane == 0) sbuf[w] = v;
    __syncthreads();
    float r = sbuf[0];
    #pragma unroll
    for (int i = 1; i < 4; ++i) {
        float o = sbuf[i];
        r = (MODE == 0) ? r + o : (MODE == 1) ? fmaxf(r, o) : fminf(r, o);
    }
    return r;
}

// ---------- prep: fp32 row -> bf16 row (+ optional row sum-of-squares), zero-pad rows ----------
__global__ void convert_rowsq(const float* __restrict__ src, u16* __restrict__ dst,
                              float* __restrict__ rowsq, int validRows) {
    __shared__ float sbuf[4];
    int r = blockIdx.x, t = threadIdx.x;
    size_t base = (size_t)r * 2048 + t * 8;
    float ss = 0.f;
    ushort4 u0 = {0,0,0,0}, u1 = {0,0,0,0};
    if (r < validRows) {
        float4 a0 = *(const float4*)(src + base);
        float4 a1 = *(const float4*)(src + base + 4);
        ss = a0.x*a0.x + a0.y*a0.y + a0.z*a0.z + a0.w*a0.w
           + a1.x*a1.x + a1.y*a1.y + a1.z*a1.z + a1.w*a1.w;
        u0.x = f2bf(a0.x); u0.y = f2bf(a0.y); u0.z = f2bf(a0.z); u0.w = f2bf(a0.w);
        u1.x = f2bf(a1.x); u1.y = f2bf(a1.y); u1.z = f2bf(a1.z); u1.w = f2bf(a1.w);
    }
    *(ushort4*)(dst + base)     = u0;
    *(ushort4*)(dst + base + 4) = u1;
    if (rowsq != nullptr) {
        ss = blockReduce<0>(ss, sbuf);
        if (t == 0) rowsq[r] = ss;
    }
}

// ---------- prep: W_cos row-normalize -> bf16, zero-pad rows ----------
__global__ void norm_rows(const float* __restrict__ src, u16* __restrict__ dst, int validRows) {
    __shared__ float sbuf[4];
    int r = blockIdx.x, t = threadIdx.x;
    size_t base = (size_t)r * 2048 + t * 8;
    ushort4 u0 = {0,0,0,0}, u1 = {0,0,0,0};
    if (r < validRows) {
        float4 a0 = *(const float4*)(src + base);
        float4 a1 = *(const float4*)(src + base + 4);
        float ss = a0.x*a0.x + a0.y*a0.y + a0.z*a0.z + a0.w*a0.w
                 + a1.x*a1.x + a1.y*a1.y + a1.z*a1.z + a1.w*a1.w;
        ss = blockReduce<0>(ss, sbuf);
        float sc = 1.f / sqrtf(ss);
        u0.x = f2bf(a0.x*sc); u0.y = f2bf(a0.y*sc); u0.z = f2bf(a0.z*sc); u0.w = f2bf(a0.w*sc);
        u1.x = f2bf(a1.x*sc); u1.y = f2bf(a1.y*sc); u1.z = f2bf(a1.z*sc); u1.w = f2bf(a1.w*sc);
    }
    *(ushort4*)(dst + base)     = u0;
    *(ushort4*)(dst + base + 4) = u1;
}

// ---------- prep: centroids [1000,2048] fp32 -> centT [2048,1024] bf16 (transposed, K-padded) ----------
__global__ void transpose_to_bf16(const float* __restrict__ src, u16* __restrict__ dst, int validRows) {
    __shared__ u16 tile[32][33];
    int d0 = blockIdx.x * 32;   // feature base (src col)
    int c0 = blockIdx.y * 32;   // class base  (src row)
    int tx = threadIdx.x, ty = threadIdx.y;
    #pragma unroll
    for (int k = 0; k < 4; ++k) {
        int c = c0 + ty + k * 8;
        float v = (c < validRows) ? src[(size_t)c * 2048 + d0 + tx] : 0.f;
        tile[ty + k * 8][tx] = f2bf(v);
    }
    __syncthreads();
    #pragma unroll
    for (int k = 0; k < 4; ++k) {
        int d = d0 + ty + k * 8;
        dst[(size_t)d * 1024 + c0 + tx] = tile[tx][ty + k * 8];
    }
}

// ---------- GEMM: C[M,N] = A[M,K]bf16 @ Bt[N,K]bf16^T, fp32 accum ----------
// 128x128 tile, BK=64, 256 threads (4 waves 2x2), each wave 64x64 via 4x4 of 16x16x32 MFMA.
// LDS layout XOR-swizzled: physical 16B-granule g of row r holds logical granule g^(r&7)
// (global_load_lds forbids padding; swizzle keeps staging segments identical, kills the
//  16-way bank conflict of the row-major layout).
// EPI: 0 = plain store; 2 = tanh(acc+bias[col]) * aux[row,col]; 3 = 16*acc, store col<nValid
template <int EPI>
__global__ __launch_bounds__(256, 2)
void gemm_bt(const u16* __restrict__ A, const u16* __restrict__ Bt, float* __restrict__ C,
             int K, int ldc, int nValid,
             const float* __restrict__ bias, const float* __restrict__ aux) {
    __shared__ u16 As[128 * 64];
    __shared__ u16 Bs[128 * 64];
    const int tid  = threadIdx.x;
    const int lane = tid & 63;
    const int w    = tid >> 6;
    const int wr   = w >> 1, wc = w & 1;
    const int quad = lane >> 4, r16 = lane & 15;
    const int sw   = r16 & 7;            // reader swizzle key
    const int lr   = lane >> 3;          // staging: row within 8-row chunk (0..7)
    const int lc   = lane & 7;           // staging: physical granule slot (0..7)
    const int lk   = (lc ^ lr) * 8;      // staging: swizzled logical k elem offset
    const size_t rowBase = (size_t)blockIdx.y * 128;
    const size_t colBase = (size_t)blockIdx.x * 128;

    f32x4 acc[4][4] = {};

    for (int kt = 0; kt < K; kt += 64) {
        #pragma unroll
        for (int i = 0; i < 4; ++i) {
            int ci = w * 4 + i;   // chunk 0..15, 8 rows each
            const u16* ga = A  + (rowBase + ci * 8 + lr) * (size_t)K + kt + lk;
            const u16* gb = Bt + (colBase + ci * 8 + lr) * (size_t)K + kt + lk;
            __builtin_amdgcn_global_load_lds(
                (const __attribute__((address_space(1))) void*)ga,
                (__attribute__((address_space(3))) void*)(As + ci * 512), 16, 0, 0);
            __builtin_amdgcn_global_load_lds(
                (const __attribute__((address_space(1))) void*)gb,
                (__attribute__((address_space(3))) void*)(Bs + ci * 512), 16, 0, 0);
        }
        __syncthreads();
        #pragma unroll
        for (int kk2 = 0; kk2 < 2; ++kk2) {
            // logical granule = kk2*4 + quad; physical = logical ^ sw (quad<4: 4|quad==4^quad)
            const int off = (((kk2 << 2) | quad) ^ sw) * 8;
            bf16x8 a[4], b[4];
            #pragma unroll
            for (int i = 0; i < 4; ++i)
                a[i] = *(const bf16x8*)(As + (wr * 64 + i * 16 + r16) * 64 + off);
            #pragma unroll
            for (int j = 0; j < 4; ++j)
                b[j] = *(const bf16x8*)(Bs + (wc * 64 + j * 16 + r16) * 64 + off);
            #pragma unroll
            for (int i = 0; i < 4; ++i)
                #pragma unroll
                for (int j = 0; j < 4; ++j)
                    acc[i][j] = __builtin_amdgcn_mfma_f32_16x16x32_bf16(a[i], b[j], acc[i][j], 0, 0, 0);
        }
        __syncthreads();
    }

    // epilogue: C/D layout col=lane&15, row=quad*4+reg (verified m89/m91)
    #pragma unroll
    for (int i = 0; i < 4; ++i) {
        #pragma unroll
        for (int j = 0; j < 4; ++j) {
            #pragma unroll
            for (int v = 0; v < 4; ++v) {
                size_t grow = rowBase + wr * 64 + i * 16 + quad * 4 + v;
                size_t gcol = colBase + wc * 64 + j * 16 + r16;
                float val = acc[i][j][v];
                if (EPI == 0) {
                    C[grow * (size_t)ldc + gcol] = val;
                } else if (EPI == 2) {
                    float t = tanhf(val + bias[gcol]);
                    C[grow * (size_t)ldc + gcol] = t * aux[grow * (size_t)ldc + gcol];
                } else if (EPI == 3) {
                    if ((int)gcol < nValid) C[grow * (size_t)ldc + gcol] = 16.0f * val;
                }
            }
        }
    }
}

// ---------- min distance -> reachability (S is [B,2048], cols 0..999 = x.cent) ----------
__global__ void min_reach(const float* __restrict__ S, const float* __restrict__ xsq,
                          const float* __restrict__ csq, float* __restrict__ reach) {
    __shared__ float sbuf[4];
    int r = blockIdx.x, t = threadIdx.x;
    float m = 1e30f;
    for (int c = t; c < 1000; c += 256)
        m = fminf(m, csq[c] - 2.f * S[(size_t)r * 2048 + c]);
    m = blockReduce<2>(m, sbuf);
    if (t == 0) {
        float d2 = xsq[r] + m;
        reach[r] = 10.f / sqrtf(fmaxf(d2, 0.f));
    }
}

// ---------- softmax over 1000 classes -> bf16 Vm [B,1024] (pad cols = 0) ----------
// H lives in S cols 1024..2047
__global__ void softmax_vm(const float* __restrict__ S, const float* __restrict__ bh,
                           u16* __restrict__ Vm) {
    __shared__ float sbuf[4];
    int r = blockIdx.x, t = threadIdx.x;
    float l[4];
    float m = -1e30f;
    #pragma unroll
    for (int i = 0; i < 4; ++i) {
        int c = t + i * 256;
        l[i] = (c < 1000) ? (S[(size_t)r * 2048 + 1024 + c] + bh[c]) : -1e30f;
        m = fmaxf(m, l[i]);
    }
    m = blockReduce<1>(m, sbuf);
    float s = 0.f;
    #pragma unroll
    for (int i = 0; i < 4; ++i) {
        int c = t + i * 256;
        l[i] = (c < 1000) ? expf(l[i] - m) : 0.f;
        s += l[i];
    }
    s = blockReduce<0>(s, sbuf);
    float inv = 1.f / s;
    #pragma unroll
    for (int i = 0; i < 4; ++i) {
        int c = t + i * 256;
        Vm[(size_t)r * 1024 + c] = f2bf(l[i] * inv);
    }
}

// ---------- fused = reach*(x+infused); ex = fused/(1+||fused||) -> bf16 ----------
__global__ void fuse_ex(const float* __restrict__ x, const float* __restrict__ inf,
                        const float* __restrict__ reach, u16* __restrict__ exh) {
    __shared__ float sbuf[4];
    int r = blockIdx.x, t = threadIdx.x;
    size_t base = (size_t)r * 2048 + t * 8;
    float4 a0 = *(const float4*)(x + base),   a1 = *(const float4*)(x + base + 4);
    float4 b0 = *(const float4*)(inf + base), b1 = *(const float4*)(inf + base + 4);
    float rr = reach[r];
    float f[8];
    f[0] = rr * (a0.x + b0.x); f[1] = rr * (a0.y + b0.y);
    f[2] = rr * (a0.z + b0.z); f[3] = rr * (a0.w + b0.w);
    f[4] = rr * (a1.x + b1.x); f[5] = rr * (a1.y + b1.y);
    f[6] = rr * (a1.z + b1.z); f[7] = rr * (a1.w + b1.w);
    float ss = 0.f;
    #pragma unroll
    for (int i = 0; i < 8; ++i) ss += f[i] * f[i];
    ss = blockReduce<0>(ss, sbuf);
    float sc = 1.f / (1.f + sqrtf(ss));
    ushort4 u0, u1;
    u0.x = f2bf(f[0]*sc); u0.y = f2bf(f[1]*sc); u0.z = f2bf(f[2]*sc); u0.w = f2bf(f[3]*sc);
    u1.x = f2bf(f[4]*sc); u1.y = f2bf(f[5]*sc); u1.z = f2bf(f[6]*sc); u1.w = f2bf(f[7]*sc);
    *(ushort4*)(exh + base)     = u0;
    *(ushort4*)(exh + base + 4) = u1;
}

extern "C" void kernel_launch(void* const* d_in, const int* in_sizes, int n_in,
                              void* d_out, int out_size, void* d_ws, size_t ws_size,
                              hipStream_t stream) {
    const float* x      = (const float*)d_in[0];   // [8192,2048]
    const float* cent   = (const float*)d_in[1];   // [1000,2048]
    const float* W_hall = (const float*)d_in[2];   // [1000,2048]
    const float* b_hall = (const float*)d_in[3];   // [1000]
    const float* W_sel  = (const float*)d_in[4];   // [2048,2048]
    const float* b_sel  = (const float*)d_in[5];   // [2048]
    const float* W_cos  = (const float*)d_in[6];   // [1000,2048]

    float* out_logits = (float*)d_out;                          // [8192,1000]
    float* out_x      = out_logits + (size_t)8192 * 1000;       // [8192,2048]
    float* out_inf    = out_x      + (size_t)8192 * 2048;       // [8192,2048]

    char* ws = (char*)d_ws;
    u16*   xh      = (u16*)  (ws);                  // 33554432 B  [8192,2048] bf16
    u16*   cent_bt = (u16*)  (ws + 33554432);       //  4194304 B  [1024,2048]   (contiguous with
    u16*   whall   = (u16*)  (ws + 37748736);       //  4194304 B  [1024,2048]    whall: merged Bt)
    u16*   wsel    = (u16*)  (ws + 41943040);       //  8388608 B  [2048,2048]
    u16*   ew      = (u16*)  (ws + 50331648);       //  4194304 B  [1024,2048]
    u16*   centT   = (u16*)  (ws + 54525952);       //  4194304 B  [2048,1024]
    float* S       = (float*)(ws + 58720256);       // 67108864 B  [8192,2048] (cols 0:1024 x.cent, 1024:2048 H)
    u16*   Vm      = (u16*)  (ws + 125829120);      // 16777216 B  [8192,1024]
    float* xsq     = (float*)(ws + 142606336);      //    32768 B
    float* csq     = (float*)(ws + 142639104);      //     4096 B
    float* reach   = (float*)(ws + 142643200);      //    32768 B
    float* memf    = S;   // alias: S dead after min_reach + softmax_vm
    u16*   exh     = xh;  // alias: xh dead after the W_sel GEMM

    (void)in_sizes; (void)n_in; (void)out_size; (void)ws_size;

    // direct_feature = x
    hipMemcpyAsync(out_x, x, (size_t)8192 * 2048 * 4, hipMemcpyDeviceToDevice, stream);

    // prep
    convert_rowsq<<<8192, 256, 0, stream>>>(x, xh, xsq, 8192);
    convert_rowsq<<<1024, 256, 0, stream>>>(cent, cent_bt, csq, 1000);
    convert_rowsq<<<1024, 256, 0, stream>>>(W_hall, whall, nullptr, 1000);
    convert_rowsq<<<2048, 256, 0, stream>>>(W_sel, wsel, nullptr, 2048);
    norm_rows<<<1024, 256, 0, stream>>>(W_cos, ew, 1000);
    transpose_to_bf16<<<dim3(64, 32), dim3(32, 8), 0, stream>>>(cent, centT, 1000);

    // S = x @ [cent | W_hall]^T  (merged N=2048)  -> reachability + softmax weights
    gemm_bt<0><<<dim3(16, 64), 256, 0, stream>>>(xh, cent_bt, S, 2048, 2048, 0, nullptr, nullptr);
    min_reach<<<8192, 256, 0, stream>>>(S, xsq, csq, reach);
    softmax_vm<<<8192, 256, 0, stream>>>(S, b_hall, Vm);

    // memf = Vm @ cent   (Bt = centT [2048,1024])  — overwrites S (dead)
    gemm_bt<0><<<dim3(16, 64), 256, 0, stream>>>(Vm, centT, memf, 1024, 2048, 0, nullptr, nullptr);

    // infused = tanh(x @ W_sel^T + b_sel) * memf   (written straight to output)
    gemm_bt<2><<<dim3(16, 64), 256, 0, stream>>>(xh, wsel, out_inf, 2048, 2048, 0, b_sel, memf);

    // ex = reach*(x+infused) / (1+norm)  -> bf16
    fuse_ex<<<8192, 256, 0, stream>>>(x, out_inf, reach, exh);

    // logits = 16 * ex @ ew^T  (store only cols < 1000)
    gemm_bt<3><<<dim3(8, 64), 256, 0, stream>>>(exh, ew, out_logits, 2048, 1000, 1000, nullptr, nullptr);
}

// Round 3
// 553.041 us; speedup vs baseline: 1.1962x; 1.0246x over previous
//
#include <hip/hip_runtime.h>
#include <hip/hip_bf16.h>

// ---------- types ----------
typedef __bf16 bf16x8 __attribute__((ext_vector_type(8)));
typedef float  f32x4  __attribute__((ext_vector_type(4)));
typedef unsigned short u16;

__device__ __forceinline__ u16 f2bf(float f) {
    __hip_bfloat16 h = __float2bfloat16(f);   // RNE
    return __builtin_bit_cast(unsigned short, h);
}
__device__ __forceinline__ float bf2f(u16 u) {
    return __bfloat162float(__builtin_bit_cast(__hip_bfloat16, u));
}

// mode: 0=sum, 1=max, 2=min   (256-thread blocks = 4 waves)
template <int MODE>
__device__ __forceinline__ float blockReduce(float v, float* sbuf) {
    #pragma unroll
    for (int off = 32; off > 0; off >>= 1) {
        float o = __shfl_down(v, off, 64);
        v = (MODE == 0) ? v + o : (MODE == 1) ? fmaxf(v, o) : fminf(v, o);
    }
    int lane = threadIdx.x & 63, w = threadIdx.x >> 6;
    __syncthreads();                 // protect sbuf from previous use
    if (lane == 0) sbuf[w] = v;
    __syncthreads();
    float r = sbuf[0];
    #pragma unroll
    for (int i = 1; i < 4; ++i) {
        float o = sbuf[i];
        r = (MODE == 0) ? r + o : (MODE == 1) ? fmaxf(r, o) : fminf(r, o);
    }
    return r;
}

// ---------- prep: fp32 row -> bf16 row (+ optional rowsq, + optional fp32 passthrough copy) ----------
__global__ void convert_rowsq(const float* __restrict__ src, u16* __restrict__ dst,
                              float* __restrict__ rowsq, float* __restrict__ copyOut,
                              int validRows) {
    __shared__ float sbuf[4];
    int r = blockIdx.x, t = threadIdx.x;
    size_t base = (size_t)r * 2048 + t * 8;
    float ss = 0.f;
    ushort4 u0 = {0,0,0,0}, u1 = {0,0,0,0};
    float4 a0 = {0,0,0,0}, a1 = {0,0,0,0};
    if (r < validRows) {
        a0 = *(const float4*)(src + base);
        a1 = *(const float4*)(src + base + 4);
        ss = a0.x*a0.x + a0.y*a0.y + a0.z*a0.z + a0.w*a0.w
           + a1.x*a1.x + a1.y*a1.y + a1.z*a1.z + a1.w*a1.w;
        u0.x = f2bf(a0.x); u0.y = f2bf(a0.y); u0.z = f2bf(a0.z); u0.w = f2bf(a0.w);
        u1.x = f2bf(a1.x); u1.y = f2bf(a1.y); u1.z = f2bf(a1.z); u1.w = f2bf(a1.w);
    }
    *(ushort4*)(dst + base)     = u0;
    *(ushort4*)(dst + base + 4) = u1;
    if (copyOut != nullptr) {
        *(float4*)(copyOut + base)     = a0;
        *(float4*)(copyOut + base + 4) = a1;
    }
    if (rowsq != nullptr) {
        ss = blockReduce<0>(ss, sbuf);
        if (t == 0) rowsq[r] = ss;
    }
}

// ---------- prep: W_cos row-normalize -> bf16, zero-pad rows ----------
__global__ void norm_rows(const float* __restrict__ src, u16* __restrict__ dst, int validRows) {
    __shared__ float sbuf[4];
    int r = blockIdx.x, t = threadIdx.x;
    size_t base = (size_t)r * 2048 + t * 8;
    ushort4 u0 = {0,0,0,0}, u1 = {0,0,0,0};
    if (r < validRows) {
        float4 a0 = *(const float4*)(src + base);
        float4 a1 = *(const float4*)(src + base + 4);
        float ss = a0.x*a0.x + a0.y*a0.y + a0.z*a0.z + a0.w*a0.w
                 + a1.x*a1.x + a1.y*a1.y + a1.z*a1.z + a1.w*a1.w;
        ss = blockReduce<0>(ss, sbuf);
        float sc = 1.f / sqrtf(ss);
        u0.x = f2bf(a0.x*sc); u0.y = f2bf(a0.y*sc); u0.z = f2bf(a0.z*sc); u0.w = f2bf(a0.w*sc);
        u1.x = f2bf(a1.x*sc); u1.y = f2bf(a1.y*sc); u1.z = f2bf(a1.z*sc); u1.w = f2bf(a1.w*sc);
    }
    *(ushort4*)(dst + base)     = u0;
    *(ushort4*)(dst + base + 4) = u1;
}

// ---------- prep: centroids [1000,2048] fp32 -> centT [2048,1024] bf16 (transposed, K-padded) ----------
__global__ void transpose_to_bf16(const float* __restrict__ src, u16* __restrict__ dst, int validRows) {
    __shared__ u16 tile[32][33];
    int d0 = blockIdx.x * 32;   // feature base (src col)
    int c0 = blockIdx.y * 32;   // class base  (src row)
    int tx = threadIdx.x, ty = threadIdx.y;
    #pragma unroll
    for (int k = 0; k < 4; ++k) {
        int c = c0 + ty + k * 8;
        float v = (c < validRows) ? src[(size_t)c * 2048 + d0 + tx] : 0.f;
        tile[ty + k * 8][tx] = f2bf(v);
    }
    __syncthreads();
    #pragma unroll
    for (int k = 0; k < 4; ++k) {
        int d = d0 + ty + k * 8;
        dst[(size_t)d * 1024 + c0 + tx] = tile[tx][ty + k * 8];
    }
}

// ---------- GEMM: C[M,N] = A[M,K]bf16 @ Bt[N,K]bf16^T, fp32 accum ----------
// 128x128 tile, BK=64, 256 threads (4 waves 2x2), each wave 64x64 via 4x4 of 16x16x32 MFMA.
// LDS XOR-swizzled (16B granule g of row r holds logical granule g^(r&7)): kills the 16-way
// conflict of row-major while keeping global_load_lds staging segments identical.
// EPI 0: plain store
// EPI 2: inf = tanh(acc+bias[col])*aux[r,c] -> C;  fused = reach[r]*(xh[r,c]+inf) -> fusedh bf16
// EPI 3: C[r,c] = bias[r]*acc  for col < nValid   (bias = per-row scale)
template <int EPI>
__global__ __launch_bounds__(256, 2)
void gemm_bt(const u16* __restrict__ A, const u16* __restrict__ Bt, float* __restrict__ C,
             int K, int ldc, int nValid,
             const float* __restrict__ bias, const float* __restrict__ aux,
             const float* __restrict__ reach, const u16* __restrict__ xh2,
             u16* __restrict__ fusedh) {
    __shared__ u16 As[128 * 64];
    __shared__ u16 Bs[128 * 64];
    const int tid  = threadIdx.x;
    const int lane = tid & 63;
    const int w    = tid >> 6;
    const int wr   = w >> 1, wc = w & 1;
    const int quad = lane >> 4, r16 = lane & 15;
    const int sw   = r16 & 7;            // reader swizzle key
    const int lr   = lane >> 3;          // staging: row within 8-row chunk (0..7)
    const int lc   = lane & 7;           // staging: physical granule slot (0..7)
    const int lk   = (lc ^ lr) * 8;      // staging: swizzled logical k elem offset
    const size_t rowBase = (size_t)blockIdx.y * 128;
    const size_t colBase = (size_t)blockIdx.x * 128;

    f32x4 acc[4][4] = {};

    for (int kt = 0; kt < K; kt += 64) {
        #pragma unroll
        for (int i = 0; i < 4; ++i) {
            int ci = w * 4 + i;   // chunk 0..15, 8 rows each
            const u16* ga = A  + (rowBase + ci * 8 + lr) * (size_t)K + kt + lk;
            const u16* gb = Bt + (colBase + ci * 8 + lr) * (size_t)K + kt + lk;
            __builtin_amdgcn_global_load_lds(
                (const __attribute__((address_space(1))) void*)ga,
                (__attribute__((address_space(3))) void*)(As + ci * 512), 16, 0, 0);
            __builtin_amdgcn_global_load_lds(
                (const __attribute__((address_space(1))) void*)gb,
                (__attribute__((address_space(3))) void*)(Bs + ci * 512), 16, 0, 0);
        }
        __syncthreads();
        #pragma unroll
        for (int kk2 = 0; kk2 < 2; ++kk2) {
            // logical granule = kk2*4 + quad; physical = logical ^ sw
            const int off = (((kk2 << 2) | quad) ^ sw) * 8;
            bf16x8 a[4], b[4];
            #pragma unroll
            for (int i = 0; i < 4; ++i)
                a[i] = *(const bf16x8*)(As + (wr * 64 + i * 16 + r16) * 64 + off);
            #pragma unroll
            for (int j = 0; j < 4; ++j)
                b[j] = *(const bf16x8*)(Bs + (wc * 64 + j * 16 + r16) * 64 + off);
            #pragma unroll
            for (int i = 0; i < 4; ++i)
                #pragma unroll
                for (int j = 0; j < 4; ++j)
                    acc[i][j] = __builtin_amdgcn_mfma_f32_16x16x32_bf16(a[i], b[j], acc[i][j], 0, 0, 0);
        }
        __syncthreads();
    }

    // epilogue: C/D layout col=lane&15, row=quad*4+reg (verified m89/m91)
    #pragma unroll
    for (int i = 0; i < 4; ++i) {
        #pragma unroll
        for (int j = 0; j < 4; ++j) {
            #pragma unroll
            for (int v = 0; v < 4; ++v) {
                size_t grow = rowBase + wr * 64 + i * 16 + quad * 4 + v;
                size_t gcol = colBase + wc * 64 + j * 16 + r16;
                float val = acc[i][j][v];
                if (EPI == 0) {
                    C[grow * (size_t)ldc + gcol] = val;
                } else if (EPI == 2) {
                    float t   = tanhf(val + bias[gcol]);
                    float inf = t * aux[grow * (size_t)ldc + gcol];
                    C[grow * (size_t)ldc + gcol] = inf;
                    float xv = bf2f(xh2[grow * (size_t)ldc + gcol]);
                    float fu = reach[grow] * (xv + inf);
                    fusedh[grow * (size_t)ldc + gcol] = f2bf(fu);
                } else if (EPI == 3) {
                    if ((int)gcol < nValid) C[grow * (size_t)ldc + gcol] = bias[grow] * val;
                }
            }
        }
    }
}

// ---------- merged: min distance -> reachability, softmax -> Vm ----------
// S is [B,2048]: cols 0..999 = x.cent, cols 1024..2023 = x.W_hall
__global__ void min_softmax(const float* __restrict__ S, const float* __restrict__ xsq,
                            const float* __restrict__ csq, const float* __restrict__ bh,
                            float* __restrict__ reach, u16* __restrict__ Vm) {
    __shared__ float sbuf[4];
    int r = blockIdx.x, t = threadIdx.x;
    // --- min distance ---
    float m = 1e30f;
    for (int c = t; c < 1000; c += 256)
        m = fminf(m, csq[c] - 2.f * S[(size_t)r * 2048 + c]);
    m = blockReduce<2>(m, sbuf);
    if (t == 0) {
        float d2 = xsq[r] + m;
        reach[r] = 10.f / sqrtf(fmaxf(d2, 0.f));
    }
    // --- softmax over 1000 classes ---
    float l[4];
    float mx = -1e30f;
    #pragma unroll
    for (int i = 0; i < 4; ++i) {
        int c = t + i * 256;
        l[i] = (c < 1000) ? (S[(size_t)r * 2048 + 1024 + c] + bh[c]) : -1e30f;
        mx = fmaxf(mx, l[i]);
    }
    mx = blockReduce<1>(mx, sbuf);
    float s = 0.f;
    #pragma unroll
    for (int i = 0; i < 4; ++i) {
        int c = t + i * 256;
        l[i] = (c < 1000) ? expf(l[i] - mx) : 0.f;
        s += l[i];
    }
    s = blockReduce<0>(s, sbuf);
    float inv = 1.f / s;
    #pragma unroll
    for (int i = 0; i < 4; ++i) {
        int c = t + i * 256;
        Vm[(size_t)r * 1024 + c] = f2bf(l[i] * inv);
    }
}

// ---------- per-row CosNorm scale: scale[r] = 16/(1+||fused_r||) ----------
__global__ void rowsq_scale(const u16* __restrict__ fusedh, float* __restrict__ scale) {
    __shared__ float sbuf[4];
    int r = blockIdx.x, t = threadIdx.x;
    size_t base = (size_t)r * 2048 + t * 8;
    ushort4 u0 = *(const ushort4*)(fusedh + base);
    ushort4 u1 = *(const ushort4*)(fusedh + base + 4);
    float f0 = bf2f(u0.x), f1 = bf2f(u0.y), f2 = bf2f(u0.z), f3 = bf2f(u0.w);
    float f4 = bf2f(u1.x), f5 = bf2f(u1.y), f6 = bf2f(u1.z), f7 = bf2f(u1.w);
    float ss = f0*f0 + f1*f1 + f2*f2 + f3*f3 + f4*f4 + f5*f5 + f6*f6 + f7*f7;
    ss = blockReduce<0>(ss, sbuf);
    if (t == 0) scale[r] = 16.f / (1.f + sqrtf(ss));
}

extern "C" void kernel_launch(void* const* d_in, const int* in_sizes, int n_in,
                              void* d_out, int out_size, void* d_ws, size_t ws_size,
                              hipStream_t stream) {
    const float* x      = (const float*)d_in[0];   // [8192,2048]
    const float* cent   = (const float*)d_in[1];   // [1000,2048]
    const float* W_hall = (const float*)d_in[2];   // [1000,2048]
    const float* b_hall = (const float*)d_in[3];   // [1000]
    const float* W_sel  = (const float*)d_in[4];   // [2048,2048]
    const float* b_sel  = (const float*)d_in[5];   // [2048]
    const float* W_cos  = (const float*)d_in[6];   // [1000,2048]

    float* out_logits = (float*)d_out;                          // [8192,1000]
    float* out_x      = out_logits + (size_t)8192 * 1000;       // [8192,2048]
    float* out_inf    = out_x      + (size_t)8192 * 2048;       // [8192,2048]

    char* ws = (char*)d_ws;
    u16*   xh      = (u16*)  (ws);                  // 33554432 B  [8192,2048] bf16
    u16*   cent_bt = (u16*)  (ws + 33554432);       //  4194304 B  [1024,2048]   (contiguous with
    u16*   whall   = (u16*)  (ws + 37748736);       //  4194304 B  [1024,2048]    whall: merged Bt)
    u16*   wsel    = (u16*)  (ws + 41943040);       //  8388608 B  [2048,2048]
    u16*   ew      = (u16*)  (ws + 50331648);       //  4194304 B  [1024,2048]
    u16*   centT   = (u16*)  (ws + 54525952);       //  4194304 B  [2048,1024]
    float* S       = (float*)(ws + 58720256);       // 67108864 B  [8192,2048] (cols 0:1024 dot, 1024:2048 H)
    u16*   Vm      = (u16*)  (ws + 125829120);      // 16777216 B  [8192,1024]
    float* xsq     = (float*)(ws + 142606336);      //    32768 B
    float* csq     = (float*)(ws + 142639104);      //     4096 B
    float* reach   = (float*)(ws + 142643200);      //    32768 B
    float* scale   = (float*)(ws + 142675968);      //    32768 B
    u16*   fusedh  = (u16*)  (ws + 142708736);      // 33554432 B  [8192,2048] bf16
    float* memf    = S;   // alias: S dead after min_softmax

    (void)in_sizes; (void)n_in; (void)out_size; (void)ws_size;

    // prep (convert x also streams the fp32 passthrough to out_x: direct_feature)
    convert_rowsq<<<8192, 256, 0, stream>>>(x, xh, xsq, out_x, 8192);
    convert_rowsq<<<1024, 256, 0, stream>>>(cent, cent_bt, csq, nullptr, 1000);
    convert_rowsq<<<1024, 256, 0, stream>>>(W_hall, whall, nullptr, nullptr, 1000);
    convert_rowsq<<<2048, 256, 0, stream>>>(W_sel, wsel, nullptr, nullptr, 2048);
    norm_rows<<<1024, 256, 0, stream>>>(W_cos, ew, 1000);
    transpose_to_bf16<<<dim3(64, 32), dim3(32, 8), 0, stream>>>(cent, centT, 1000);

    // S = x @ [cent | W_hall]^T  (merged N=2048)  -> reachability + softmax weights
    gemm_bt<0><<<dim3(16, 64), 256, 0, stream>>>(xh, cent_bt, S, 2048, 2048, 0,
                                                 nullptr, nullptr, nullptr, nullptr, nullptr);
    min_softmax<<<8192, 256, 0, stream>>>(S, xsq, csq, b_hall, reach, Vm);

    // memf = Vm @ cent   (Bt = centT [2048,1024])  — overwrites S (dead)
    gemm_bt<0><<<dim3(16, 64), 256, 0, stream>>>(Vm, centT, memf, 1024, 2048, 0,
                                                 nullptr, nullptr, nullptr, nullptr, nullptr);

    // infused = tanh(x @ W_sel^T + b_sel) * memf -> out_inf;  fused bf16 -> fusedh
    gemm_bt<2><<<dim3(16, 64), 256, 0, stream>>>(xh, wsel, out_inf, 2048, 2048, 0,
                                                 b_sel, memf, reach, xh, fusedh);

    // per-row CosNorm scale
    rowsq_scale<<<8192, 256, 0, stream>>>(fusedh, scale);

    // logits = scale[row] * (fused @ ew^T)  (store only cols < 1000)
    gemm_bt<3><<<dim3(8, 64), 256, 0, stream>>>(fusedh, ew, out_logits, 2048, 1000, 1000,
                                                scale, nullptr, nullptr, nullptr, nullptr);
}

// Round 4
// 538.079 us; speedup vs baseline: 1.2295x; 1.0278x over previous
//
#include <hip/hip_runtime.h>
#include <hip/hip_bf16.h>

// ---------- types ----------
typedef __bf16 bf16x8 __attribute__((ext_vector_type(8)));
typedef float  f32x4  __attribute__((ext_vector_type(4)));
typedef unsigned short u16;

__device__ __forceinline__ u16 f2bf(float f) {
    __hip_bfloat16 h = __float2bfloat16(f);   // RNE
    return __builtin_bit_cast(unsigned short, h);
}
__device__ __forceinline__ float bf2f(u16 u) {
    return __bfloat162float(__builtin_bit_cast(__hip_bfloat16, u));
}

// mode: 0=sum, 1=max, 2=min   (256-thread blocks = 4 waves)
template <int MODE>
__device__ __forceinline__ float blockReduce(float v, float* sbuf) {
    #pragma unroll
    for (int off = 32; off > 0; off >>= 1) {
        float o = __shfl_down(v, off, 64);
        v = (MODE == 0) ? v + o : (MODE == 1) ? fmaxf(v, o) : fminf(v, o);
    }
    int lane = threadIdx.x & 63, w = threadIdx.x >> 6;
    __syncthreads();                 // protect sbuf from previous use
    if (lane == 0) sbuf[w] = v;
    __syncthreads();
    float r = sbuf[0];
    #pragma unroll
    for (int i = 1; i < 4; ++i) {
        float o = sbuf[i];
        r = (MODE == 0) ? r + o : (MODE == 1) ? fmaxf(r, o) : fminf(r, o);
    }
    return r;
}

// ---------- prep: x fp32 -> xh bf16 + xsq + fp32 passthrough to out_x ----------
__global__ void convert_x(const float* __restrict__ src, u16* __restrict__ dst,
                          float* __restrict__ rowsq, float* __restrict__ copyOut) {
    __shared__ float sbuf[4];
    int r = blockIdx.x, t = threadIdx.x;
    size_t base = (size_t)r * 2048 + t * 8;
    float4 a0 = *(const float4*)(src + base);
    float4 a1 = *(const float4*)(src + base + 4);
    float ss = a0.x*a0.x + a0.y*a0.y + a0.z*a0.z + a0.w*a0.w
             + a1.x*a1.x + a1.y*a1.y + a1.z*a1.z + a1.w*a1.w;
    ushort4 u0, u1;
    u0.x = f2bf(a0.x); u0.y = f2bf(a0.y); u0.z = f2bf(a0.z); u0.w = f2bf(a0.w);
    u1.x = f2bf(a1.x); u1.y = f2bf(a1.y); u1.z = f2bf(a1.z); u1.w = f2bf(a1.w);
    *(ushort4*)(dst + base)     = u0;
    *(ushort4*)(dst + base + 4) = u1;
    *(float4*)(copyOut + base)     = a0;
    *(float4*)(copyOut + base + 4) = a1;
    ss = blockReduce<0>(ss, sbuf);
    if (t == 0) rowsq[r] = ss;
}

// ---------- prep: merged weight convert -> Bp [4096,2048] bf16 ----------
// rows 0..1023 = cent (valid<1000, csq), 1024..2047 = W_hall (valid<1000), 2048..4095 = W_sel
__global__ void convert_weights(const float* __restrict__ cent, const float* __restrict__ whall,
                                const float* __restrict__ wsel, u16* __restrict__ Bp,
                                float* __restrict__ csq) {
    __shared__ float sbuf[4];
    int r = blockIdx.x, t = threadIdx.x;
    const float* src; int sr; bool valid;
    if (r < 1024)       { src = cent;  sr = r;        valid = sr < 1000; }
    else if (r < 2048)  { src = whall; sr = r - 1024; valid = sr < 1000; }
    else                { src = wsel;  sr = r - 2048; valid = true; }
    size_t dbase = (size_t)r * 2048 + t * 8;
    float ss = 0.f;
    ushort4 u0 = {0,0,0,0}, u1 = {0,0,0,0};
    if (valid) {
        size_t sbase = (size_t)sr * 2048 + t * 8;
        float4 a0 = *(const float4*)(src + sbase);
        float4 a1 = *(const float4*)(src + sbase + 4);
        ss = a0.x*a0.x + a0.y*a0.y + a0.z*a0.z + a0.w*a0.w
           + a1.x*a1.x + a1.y*a1.y + a1.z*a1.z + a1.w*a1.w;
        u0.x = f2bf(a0.x); u0.y = f2bf(a0.y); u0.z = f2bf(a0.z); u0.w = f2bf(a0.w);
        u1.x = f2bf(a1.x); u1.y = f2bf(a1.y); u1.z = f2bf(a1.z); u1.w = f2bf(a1.w);
    }
    *(ushort4*)(Bp + dbase)     = u0;
    *(ushort4*)(Bp + dbase + 4) = u1;
    if (r < 1024) {
        ss = blockReduce<0>(ss, sbuf);
        if (t == 0) csq[r] = ss;
    }
}

// ---------- prep: W_cos row-normalize -> bf16, zero-pad rows ----------
__global__ void norm_rows(const float* __restrict__ src, u16* __restrict__ dst, int validRows) {
    __shared__ float sbuf[4];
    int r = blockIdx.x, t = threadIdx.x;
    size_t base = (size_t)r * 2048 + t * 8;
    ushort4 u0 = {0,0,0,0}, u1 = {0,0,0,0};
    if (r < validRows) {
        float4 a0 = *(const float4*)(src + base);
        float4 a1 = *(const float4*)(src + base + 4);
        float ss = a0.x*a0.x + a0.y*a0.y + a0.z*a0.z + a0.w*a0.w
                 + a1.x*a1.x + a1.y*a1.y + a1.z*a1.z + a1.w*a1.w;
        ss = blockReduce<0>(ss, sbuf);
        float sc = 1.f / sqrtf(ss);
        u0.x = f2bf(a0.x*sc); u0.y = f2bf(a0.y*sc); u0.z = f2bf(a0.z*sc); u0.w = f2bf(a0.w*sc);
        u1.x = f2bf(a1.x*sc); u1.y = f2bf(a1.y*sc); u1.z = f2bf(a1.z*sc); u1.w = f2bf(a1.w*sc);
    }
    *(ushort4*)(dst + base)     = u0;
    *(ushort4*)(dst + base + 4) = u1;
}

// ---------- prep: centroids [1000,2048] fp32 -> centT [2048,1024] bf16 (transposed, K-padded) ----------
__global__ void transpose_to_bf16(const float* __restrict__ src, u16* __restrict__ dst, int validRows) {
    __shared__ u16 tile[32][33];
    int d0 = blockIdx.x * 32;   // feature base (src col)
    int c0 = blockIdx.y * 32;   // class base  (src row)
    int tx = threadIdx.x, ty = threadIdx.y;
    #pragma unroll
    for (int k = 0; k < 4; ++k) {
        int c = c0 + ty + k * 8;
        float v = (c < validRows) ? src[(size_t)c * 2048 + d0 + tx] : 0.f;
        tile[ty + k * 8][tx] = f2bf(v);
    }
    __syncthreads();
    #pragma unroll
    for (int k = 0; k < 4; ++k) {
        int d = d0 + ty + k * 8;
        dst[(size_t)d * 1024 + c0 + tx] = tile[tx][ty + k * 8];
    }
}

// ---------- GEMM: C[M,N] = A[M,K]bf16 @ Bt[N,K]bf16^T, fp32 accum ----------
// 128x128 tile, BK=64, 256 threads (4 waves 2x2), each wave 64x64 via 4x4 of 16x16x32 MFMA.
// LDS XOR-swizzled (16B granule g of row r holds logical granule g^(r&7)): conflict-free
// while keeping global_load_lds staging segments identical.
// EPI 1: bf16 store to Cb
// EPI 2: acc = memf; inf = tanh(sel[r,c]+bias[c])*acc -> Cf (fp32);
//        fused = reach[r]*(xh[r,c]+inf) -> fusedh (bf16)
// EPI 3: Cf[r,c] = bias[r]*acc  for col < nValid  (bias = per-row CosNorm scale)
template <int EPI>
__global__ __launch_bounds__(256, 4)
void gemm_bt(const u16* __restrict__ A, const u16* __restrict__ Bt,
             float* __restrict__ Cf, u16* __restrict__ Cb,
             int K, int ldc, int nValid,
             const float* __restrict__ bias,
             const u16* __restrict__ selp, int ldsel,
             const float* __restrict__ reach, const u16* __restrict__ xh2,
             u16* __restrict__ fusedh) {
    __shared__ u16 As[128 * 64];
    __shared__ u16 Bs[128 * 64];
    const int tid  = threadIdx.x;
    const int lane = tid & 63;
    const int w    = tid >> 6;
    const int wr   = w >> 1, wc = w & 1;
    const int quad = lane >> 4, r16 = lane & 15;
    const int sw   = r16 & 7;            // reader swizzle key
    const int lr   = lane >> 3;          // staging: row within 8-row chunk (0..7)
    const int lc   = lane & 7;           // staging: physical granule slot (0..7)
    const int lk   = (lc ^ lr) * 8;      // staging: swizzled logical k elem offset
    const size_t rowBase = (size_t)blockIdx.y * 128;
    const size_t colBase = (size_t)blockIdx.x * 128;

    f32x4 acc[4][4] = {};

    for (int kt = 0; kt < K; kt += 64) {
        #pragma unroll
        for (int i = 0; i < 4; ++i) {
            int ci = w * 4 + i;   // chunk 0..15, 8 rows each
            const u16* ga = A  + (rowBase + ci * 8 + lr) * (size_t)K + kt + lk;
            const u16* gb = Bt + (colBase + ci * 8 + lr) * (size_t)K + kt + lk;
            __builtin_amdgcn_global_load_lds(
                (const __attribute__((address_space(1))) void*)ga,
                (__attribute__((address_space(3))) void*)(As + ci * 512), 16, 0, 0);
            __builtin_amdgcn_global_load_lds(
                (const __attribute__((address_space(1))) void*)gb,
                (__attribute__((address_space(3))) void*)(Bs + ci * 512), 16, 0, 0);
        }
        __syncthreads();
        #pragma unroll
        for (int kk2 = 0; kk2 < 2; ++kk2) {
            // logical granule = kk2*4 + quad; physical = logical ^ sw
            const int off = (((kk2 << 2) | quad) ^ sw) * 8;
            bf16x8 a[4], b[4];
            #pragma unroll
            for (int i = 0; i < 4; ++i)
                a[i] = *(const bf16x8*)(As + (wr * 64 + i * 16 + r16) * 64 + off);
            #pragma unroll
            for (int j = 0; j < 4; ++j)
                b[j] = *(const bf16x8*)(Bs + (wc * 64 + j * 16 + r16) * 64 + off);
            #pragma unroll
            for (int i = 0; i < 4; ++i)
                #pragma unroll
                for (int j = 0; j < 4; ++j)
                    acc[i][j] = __builtin_amdgcn_mfma_f32_16x16x32_bf16(a[i], b[j], acc[i][j], 0, 0, 0);
        }
        __syncthreads();
    }

    // epilogue: C/D layout col=lane&15, row=quad*4+reg (verified m89/m91)
    #pragma unroll
    for (int i = 0; i < 4; ++i) {
        #pragma unroll
        for (int j = 0; j < 4; ++j) {
            #pragma unroll
            for (int v = 0; v < 4; ++v) {
                size_t grow = rowBase + wr * 64 + i * 16 + quad * 4 + v;
                size_t gcol = colBase + wc * 64 + j * 16 + r16;
                float val = acc[i][j][v];
                if (EPI == 1) {
                    Cb[grow * (size_t)ldc + gcol] = f2bf(val);
                } else if (EPI == 2) {
                    float sv  = bf2f(selp[grow * (size_t)ldsel + gcol]);
                    float t   = tanhf(sv + bias[gcol]);
                    float inf = t * val;
                    Cf[grow * (size_t)ldc + gcol] = inf;
                    float xv = bf2f(xh2[grow * (size_t)ldc + gcol]);
                    fusedh[grow * (size_t)ldc + gcol] = f2bf(reach[grow] * (xv + inf));
                } else if (EPI == 3) {
                    if ((int)gcol < nValid) Cf[grow * (size_t)ldc + gcol] = bias[grow] * val;
                }
            }
        }
    }
}

// ---------- merged: min distance -> reachability, softmax -> Vm ----------
// Sp is [B,4096] bf16: cols 0..999 = x.cent, 1024..2023 = x.W_hall (2048..4095 = sel, unused here)
__global__ void min_softmax(const u16* __restrict__ Sp, const float* __restrict__ xsq,
                            const float* __restrict__ csq, const float* __restrict__ bh,
                            float* __restrict__ reach, u16* __restrict__ Vm) {
    __shared__ float sbuf[4];
    int r = blockIdx.x, t = threadIdx.x;
    size_t rb = (size_t)r * 4096;
    // --- min distance ---
    float m = 1e30f;
    for (int c = t; c < 1000; c += 256)
        m = fminf(m, csq[c] - 2.f * bf2f(Sp[rb + c]));
    m = blockReduce<2>(m, sbuf);
    if (t == 0) {
        float d2 = xsq[r] + m;
        reach[r] = 10.f / sqrtf(fmaxf(d2, 0.f));
    }
    // --- softmax over 1000 classes ---
    float l[4];
    float mx = -1e30f;
    #pragma unroll
    for (int i = 0; i < 4; ++i) {
        int c = t + i * 256;
        l[i] = (c < 1000) ? (bf2f(Sp[rb + 1024 + c]) + bh[c]) : -1e30f;
        mx = fmaxf(mx, l[i]);
    }
    mx = blockReduce<1>(mx, sbuf);
    float s = 0.f;
    #pragma unroll
    for (int i = 0; i < 4; ++i) {
        int c = t + i * 256;
        l[i] = (c < 1000) ? expf(l[i] - mx) : 0.f;
        s += l[i];
    }
    s = blockReduce<0>(s, sbuf);
    float inv = 1.f / s;
    #pragma unroll
    for (int i = 0; i < 4; ++i) {
        int c = t + i * 256;
        Vm[(size_t)r * 1024 + c] = f2bf(l[i] * inv);
    }
}

// ---------- per-row CosNorm scale: scale[r] = 16/(1+||fused_r||) ----------
__global__ void rowsq_scale(const u16* __restrict__ fusedh, float* __restrict__ scale) {
    __shared__ float sbuf[4];
    int r = blockIdx.x, t = threadIdx.x;
    size_t base = (size_t)r * 2048 + t * 8;
    ushort4 u0 = *(const ushort4*)(fusedh + base);
    ushort4 u1 = *(const ushort4*)(fusedh + base + 4);
    float f0 = bf2f(u0.x), f1 = bf2f(u0.y), f2 = bf2f(u0.z), f3 = bf2f(u0.w);
    float f4 = bf2f(u1.x), f5 = bf2f(u1.y), f6 = bf2f(u1.z), f7 = bf2f(u1.w);
    float ss = f0*f0 + f1*f1 + f2*f2 + f3*f3 + f4*f4 + f5*f5 + f6*f6 + f7*f7;
    ss = blockReduce<0>(ss, sbuf);
    if (t == 0) scale[r] = 16.f / (1.f + sqrtf(ss));
}

extern "C" void kernel_launch(void* const* d_in, const int* in_sizes, int n_in,
                              void* d_out, int out_size, void* d_ws, size_t ws_size,
                              hipStream_t stream) {
    const float* x      = (const float*)d_in[0];   // [8192,2048]
    const float* cent   = (const float*)d_in[1];   // [1000,2048]
    const float* W_hall = (const float*)d_in[2];   // [1000,2048]
    const float* b_hall = (const float*)d_in[3];   // [1000]
    const float* W_sel  = (const float*)d_in[4];   // [2048,2048]
    const float* b_sel  = (const float*)d_in[5];   // [2048]
    const float* W_cos  = (const float*)d_in[6];   // [1000,2048]

    float* out_logits = (float*)d_out;                          // [8192,1000]
    float* out_x      = out_logits + (size_t)8192 * 1000;       // [8192,2048]
    float* out_inf    = out_x      + (size_t)8192 * 2048;       // [8192,2048]

    char* ws = (char*)d_ws;
    u16*   xh     = (u16*)  (ws);                  // 33554432 B  [8192,2048] bf16
    u16*   Bp     = (u16*)  (ws + 33554432);       // 16777216 B  [4096,2048] bf16: cent|W_hall|W_sel
    u16*   ew     = (u16*)  (ws + 50331648);       //  4194304 B  [1024,2048]
    u16*   centT  = (u16*)  (ws + 54525952);       //  4194304 B  [2048,1024]
    u16*   Sp     = (u16*)  (ws + 58720256);       // 67108864 B  [8192,4096] bf16 (dot|H|sel)
    u16*   Vm     = (u16*)  (ws + 125829120);      // 16777216 B  [8192,1024] bf16
    u16*   fusedh = (u16*)  (ws + 142606336);      // 33554432 B  [8192,2048] bf16
    float* xsq    = (float*)(ws + 176160768);      //    32768 B
    float* csq    = (float*)(ws + 176193536);      //     4096 B
    float* reach  = (float*)(ws + 176197632);      //    32768 B
    float* scale  = (float*)(ws + 176230400);      //    32768 B

    (void)in_sizes; (void)n_in; (void)out_size; (void)ws_size;

    // prep (convert_x also streams the fp32 passthrough to out_x: direct_feature)
    convert_x<<<8192, 256, 0, stream>>>(x, xh, xsq, out_x);
    convert_weights<<<4096, 256, 0, stream>>>(cent, W_hall, W_sel, Bp, csq);
    norm_rows<<<1024, 256, 0, stream>>>(W_cos, ew, 1000);
    transpose_to_bf16<<<dim3(64, 32), dim3(32, 8), 0, stream>>>(cent, centT, 1000);

    // GEMM-A: Sp = x @ [cent | W_hall | W_sel]^T  (N=4096, bf16 out)
    gemm_bt<1><<<dim3(32, 64), 256, 0, stream>>>(xh, Bp, nullptr, Sp, 2048, 4096, 0,
                                                 nullptr, nullptr, 0, nullptr, nullptr, nullptr);
    min_softmax<<<8192, 256, 0, stream>>>(Sp, xsq, csq, b_hall, reach, Vm);

    // GEMM-B: acc = Vm @ cent (memf); epilogue: inf=tanh(sel+b_sel)*acc -> out_inf,
    //         fused=reach*(x+inf) -> fusedh
    gemm_bt<2><<<dim3(16, 64), 256, 0, stream>>>(Vm, centT, out_inf, nullptr, 1024, 2048, 0,
                                                 b_sel, Sp + 2048, 4096, reach, xh, fusedh);

    // per-row CosNorm scale
    rowsq_scale<<<8192, 256, 0, stream>>>(fusedh, scale);

    // GEMM-C: logits = scale[row] * (fused @ ew^T)  (store only cols < 1000)
    gemm_bt<3><<<dim3(8, 64), 256, 0, stream>>>(fusedh, ew, out_logits, nullptr, 2048, 1000, 1000,
                                                scale, nullptr, 0, nullptr, nullptr, nullptr);
}